// Round 2
// baseline (639.197 us; speedup 1.0000x reference)
//
#include <hip/hip_runtime.h>
#include <hip/hip_fp16.h>

#define NB    64
#define CIN   96
#define MIDC  576
#define COUT  96
#define HW    784
#define W28   28
#define NX    4816896        /* 64*96*28*28  */
#define NY    28901376ull    /* 64*576*28*28 */

// ---------------- helpers ----------------

__device__ __forceinline__ float wave_max64(float v){
  #pragma unroll
  for(int i=32;i>=1;i>>=1) v = fmaxf(v, __shfl_xor(v, i, 64));
  return v;
}

__device__ __forceinline__ void block_max_atomic(float v, unsigned* dst){
  v = wave_max64(v);
  __shared__ float sm[8];
  int lane = threadIdx.x & 63, w = threadIdx.x >> 6;
  if(lane==0) sm[w] = v;
  __syncthreads();
  if(threadIdx.x==0){
    int nw = (blockDim.x + 63) >> 6;
    float m = sm[0];
    for(int i=1;i<nw;i++) m = fmaxf(m, sm[i]);
    atomicMax(dst, __float_as_uint(m));   // v>=0 always: uint order == float order
  }
}

// fake-quant one value given scale s (true division, round-half-even like jnp.round)
__device__ __forceinline__ float fq(float x, float s){
  float q = rintf(x / s);
  q = fminf(fmaxf(q, -127.f), 127.f);
  return q * s;
}

// reciprocal-mult variant for the 9x-redundant depthwise taps
__device__ __forceinline__ float fqr(float x, float r, float s){
  float q = rintf(x * r);
  q = fminf(fmaxf(q, -127.f), 127.f);
  return q * s;
}

// ---------------- kernels ----------------

__global__ void k_init(unsigned* umax){
  if(threadIdx.x < 4) umax[threadIdx.x] = 0u;
}

// BN-fold + per-channel weight fake-quant. 1248 blocks x 64 threads (1 wave each).
__global__ void k_prep(const float* __restrict__ w1,const float* __restrict__ g1,const float* __restrict__ b1,const float* __restrict__ m1,const float* __restrict__ v1,
                       const float* __restrict__ w2,const float* __restrict__ g2,const float* __restrict__ b2,const float* __restrict__ m2,const float* __restrict__ v2,
                       const float* __restrict__ w3,const float* __restrict__ g3,const float* __restrict__ b3,const float* __restrict__ m3,const float* __restrict__ v3,
                       float* __restrict__ wq1, float* __restrict__ bq1,
                       float* __restrict__ wq2, float* __restrict__ bq2,
                       float* __restrict__ wq3T, float* __restrict__ bq3)
{
  int b = blockIdx.x, lane = threadIdx.x;
  if(b < MIDC){                                   // conv1 weights: row o, 96 elems
    int o = b;
    float f = g1[o] / sqrtf(v1[o] + 1e-5f);
    float x0 = w1[o*CIN + lane] * f;
    float x1 = (lane < CIN-64) ? w1[o*CIN + 64 + lane] * f : 0.f;
    float m = wave_max64(fmaxf(fabsf(x0), fabsf(x1)));
    float s = m / 127.f + 1e-8f;
    wq1[o*CIN + lane] = fq(x0, s);
    if(lane < CIN-64) wq1[o*CIN + 64 + lane] = fq(x1, s);
    if(lane==0) bq1[o] = b1[o] - m1[o]*f;
  } else if(b < 2*MIDC){                          // depthwise weights: channel c, 9 elems
    int c = b - MIDC;
    float f = g2[c] / sqrtf(v2[c] + 1e-5f);
    float x0 = (lane < 9) ? w2[c*9 + lane] * f : 0.f;
    float m = wave_max64(fabsf(x0));
    float s = m / 127.f + 1e-8f;
    if(lane < 9) wq2[c*9 + lane] = fq(x0, s);
    if(lane==0) bq2[c] = b2[c] - m2[c]*f;
  } else {                                        // conv3 weights: out channel o, 576 elems; store transposed [c][o]
    int o = b - 2*MIDC;
    float f = g3[o] / sqrtf(v3[o] + 1e-5f);
    float xs[9]; float m = 0.f;
    #pragma unroll
    for(int k=0;k<9;k++){ int c = lane + 64*k; xs[k] = w3[o*MIDC + c] * f; m = fmaxf(m, fabsf(xs[k])); }
    m = wave_max64(m);
    float s = m / 127.f + 1e-8f;
    #pragma unroll
    for(int k=0;k<9;k++){ int c = lane + 64*k; wq3T[(size_t)c*COUT + o] = fq(xs[k], s); }
    if(lane==0) bq3[o] = b3[o] - m3[o]*f;
  }
}

__global__ void k_absmax(const float4* __restrict__ x, int n4, unsigned* dst){
  float m = 0.f;
  for(int i = blockIdx.x*blockDim.x + threadIdx.x; i < n4; i += gridDim.x*blockDim.x){
    float4 v = x[i];
    m = fmaxf(m, fmaxf(fmaxf(fabsf(v.x), fabsf(v.y)), fmaxf(fabsf(v.z), fabsf(v.w))));
  }
  block_max_atomic(m, dst);
}

// 1x1 conv 96->576 + bias + ReLU6, quantizing x on the fly. grid (196, 4), o-chunk 144.
template<typename T>
__global__ __launch_bounds__(256) void k_conv1(const float* __restrict__ x, const float* __restrict__ wq1,
     const float* __restrict__ bq1, unsigned* umax, T* __restrict__ y1)
{
  int tid = blockIdx.x*256 + threadIdx.x;       // 0..50175 = n*784+p
  int n = tid / HW, p = tid - n*HW;
  float s0 = __uint_as_float(umax[0]) / 127.f + 1e-8f;
  float xq[CIN];
  const float* xp = x + (size_t)n*CIN*HW + p;
  #pragma unroll
  for(int c=0;c<CIN;c++) xq[c] = fq(xp[(size_t)c*HW], s0);
  int ob = blockIdx.y * 144;
  T* yp = y1 + (size_t)n*MIDC*HW + p;
  float tmax = 0.f;
  for(int oo=0;oo<144;oo++){
    int o = ob + oo;
    const float* __restrict__ wr = wq1 + o*CIN;  // o is wave-uniform -> scalar loads
    float acc = bq1[o];
    #pragma unroll
    for(int c=0;c<CIN;c++) acc = fmaf(xq[c], wr[c], acc);
    acc = fminf(fmaxf(acc, 0.f), 6.f);
    tmax = fmaxf(tmax, acc);
    yp[(size_t)o*HW] = (T)acc;
  }
  block_max_atomic(tmax, umax + 1);
}

// depthwise 3x3, pad 1 + bias + ReLU6, quantizing y1 on read. grid-stride.
template<typename T>
__global__ __launch_bounds__(256) void k_conv2(const T* __restrict__ y1, const float* __restrict__ wq2,
   const float* __restrict__ bq2, unsigned* umax, T* __restrict__ y2)
{
  float s1 = __uint_as_float(umax[1]) / 127.f + 1e-8f;
  float r1 = 1.f / s1;
  float tmax = 0.f;
  for(size_t tid = (size_t)blockIdx.x*blockDim.x + threadIdx.x; tid < NY; tid += (size_t)gridDim.x*blockDim.x){
    int p = (int)(tid % HW); size_t nc = tid / HW; int c = (int)(nc % MIDC);
    int h = p / W28, w = p - h*W28;
    const T* bp = y1 + nc*HW;
    const float* wr = wq2 + c*9;
    float acc = bq2[c];
    #pragma unroll
    for(int dy=-1;dy<=1;dy++){
      #pragma unroll
      for(int dx=-1;dx<=1;dx++){
        int hh = h+dy, ww = w+dx;
        float v = (hh>=0 && hh<W28 && ww>=0 && ww<W28) ? (float)bp[hh*W28 + ww] : 0.f;
        acc = fmaf(fqr(v, r1, s1), wr[(dy+1)*3 + (dx+1)], acc);
      }
    }
    acc = fminf(fmaxf(acc, 0.f), 6.f);
    tmax = fmaxf(tmax, acc);
    y2[tid] = (T)acc;
  }
  block_max_atomic(tmax, umax + 2);
}

// 1x1 conv 576->96 + bias + identity, write pre-quant to out. 196 blocks x 256.
template<typename T>
__global__ __launch_bounds__(256) void k_conv3(const T* __restrict__ y2, const float* __restrict__ wq3T,
   const float* __restrict__ bq3, const float* __restrict__ x, unsigned* umax,
   float* __restrict__ out)
{
  int tid = blockIdx.x*256 + threadIdx.x;
  int n = tid / HW, p = tid - n*HW;
  float s2 = __uint_as_float(umax[2]) / 127.f + 1e-8f;
  float acc[COUT];
  #pragma unroll
  for(int o=0;o<COUT;o++) acc[o] = bq3[o];
  const T* yp = y2 + (size_t)n*MIDC*HW + p;
  for(int c=0;c<MIDC;c+=4){
    float q0 = fq((float)yp[(size_t)(c+0)*HW], s2);
    float q1 = fq((float)yp[(size_t)(c+1)*HW], s2);
    float q2 = fq((float)yp[(size_t)(c+2)*HW], s2);
    float q3 = fq((float)yp[(size_t)(c+3)*HW], s2);
    const float* w0 = wq3T + (size_t)c*COUT;     // c is wave-uniform -> scalar loads
    #pragma unroll
    for(int o=0;o<COUT;o++){
      float a = acc[o];
      a = fmaf(q0, w0[o],         a);
      a = fmaf(q1, w0[COUT+o],    a);
      a = fmaf(q2, w0[2*COUT+o],  a);
      a = fmaf(q3, w0[3*COUT+o],  a);
      acc[o] = a;
    }
  }
  const float* xp = x + (size_t)n*CIN*HW + p;
  float* op = out + (size_t)n*CIN*HW + p;
  float tmax = 0.f;
  #pragma unroll
  for(int o=0;o<COUT;o++){
    float y = acc[o] + xp[(size_t)o*HW];
    tmax = fmaxf(tmax, fabsf(y));
    op[(size_t)o*HW] = y;
  }
  block_max_atomic(tmax, umax + 3);
}

// final per-tensor fake-quant of out (in place) + write scale
__global__ void k_finalq(float* __restrict__ out, const unsigned* __restrict__ umax, float* __restrict__ sf){
  int i = blockIdx.x*blockDim.x + threadIdx.x;
  float s3 = __uint_as_float(umax[3]) / 127.f + 1e-8f;
  int n4 = NX/4;
  if(i < n4){
    float4* o4 = (float4*)out;
    float4 v = o4[i];
    v.x = fq(v.x, s3); v.y = fq(v.y, s3); v.z = fq(v.z, s3); v.w = fq(v.w, s3);
    o4[i] = v;
  }
  if(i == 0) *sf = s3;
}

// ---------------- launch ----------------

extern "C" void kernel_launch(void* const* d_in, const int* in_sizes, int n_in,
                              void* d_out, int out_size, void* d_ws, size_t ws_size,
                              hipStream_t stream)
{
  const float* x  = (const float*)d_in[0];
  const float* w1 = (const float*)d_in[1];
  const float* g1 = (const float*)d_in[2];
  const float* b1 = (const float*)d_in[3];
  const float* m1 = (const float*)d_in[4];
  const float* v1 = (const float*)d_in[5];
  const float* w2 = (const float*)d_in[6];
  const float* g2 = (const float*)d_in[7];
  const float* b2 = (const float*)d_in[8];
  const float* m2 = (const float*)d_in[9];
  const float* v2 = (const float*)d_in[10];
  const float* w3 = (const float*)d_in[11];
  const float* g3 = (const float*)d_in[12];
  const float* b3 = (const float*)d_in[13];
  const float* m3 = (const float*)d_in[14];
  const float* v3 = (const float*)d_in[15];

  char* ws = (char*)d_ws;
  unsigned* umax = (unsigned*)(ws + 0);
  float* bq1  = (float*)(ws + 64);
  float* bq2  = (float*)(ws + 2368);
  float* bq3  = (float*)(ws + 4672);
  float* wq1  = (float*)(ws + 5056);
  float* wq2  = (float*)(ws + 226240);
  float* wq3T = (float*)(ws + 246976);
  char*  ybase = ws + 468224;

  float* outp = (float*)d_out;
  bool fp32path = (ws_size >= 231679232ull);   // 2 fp32 intermediates of 115.6MB

  k_init<<<1, 64, 0, stream>>>(umax);
  k_prep<<<1248, 64, 0, stream>>>(w1,g1,b1,m1,v1, w2,g2,b2,m2,v2, w3,g3,b3,m3,v3,
                                  wq1,bq1, wq2,bq2, wq3T,bq3);
  k_absmax<<<1024, 256, 0, stream>>>((const float4*)x, NX/4, umax + 0);

  if(fp32path){
    float* y1 = (float*)ybase;
    float* y2 = y1 + NY;
    k_conv1<float><<<dim3(196,4), 256, 0, stream>>>(x, wq1, bq1, umax, y1);
    k_conv2<float><<<8192, 256, 0, stream>>>(y1, wq2, bq2, umax, y2);
    k_conv3<float><<<196, 256, 0, stream>>>(y2, wq3T, bq3, x, umax, outp);
  } else {
    __half* y1 = (__half*)ybase;
    __half* y2 = y1 + NY;
    k_conv1<__half><<<dim3(196,4), 256, 0, stream>>>(x, wq1, bq1, umax, y1);
    k_conv2<__half><<<8192, 256, 0, stream>>>(y1, wq2, bq2, umax, y2);
    k_conv3<__half><<<196, 256, 0, stream>>>(y2, wq3T, bq3, x, umax, outp);
  }

  k_finalq<<<(NX/4 + 255)/256, 256, 0, stream>>>(outp, umax, outp + NX);
}

// Round 3
// 361.189 us; speedup vs baseline: 1.7697x; 1.7697x over previous
//
#include <hip/hip_runtime.h>
#include <hip/hip_fp16.h>

#define NB    64
#define CIN   96
#define MIDC  576
#define COUT  96
#define HW    784
#define W28   28
#define NX    4816896        /* 64*96*28*28  */
#define NY    28901376       /* 64*576*28*28 (fits int32) */

// ---------------- helpers ----------------

__device__ __forceinline__ float wave_max64(float v){
  #pragma unroll
  for(int i=32;i>=1;i>>=1) v = fmaxf(v, __shfl_xor(v, i, 64));
  return v;
}

__device__ __forceinline__ void block_max_atomic(float v, unsigned* dst){
  v = wave_max64(v);
  __shared__ float sm[8];
  int lane = threadIdx.x & 63, w = threadIdx.x >> 6;
  if(lane==0) sm[w] = v;
  __syncthreads();
  if(threadIdx.x==0){
    int nw = (blockDim.x + 63) >> 6;
    float m = sm[0];
    for(int i=1;i<nw;i++) m = fmaxf(m, sm[i]);
    atomicMax(dst, __float_as_uint(m));   // v>=0 always: uint order == float order
  }
}

// fake-quant, true division (round-half-even like jnp.round)
__device__ __forceinline__ float fq(float x, float s){
  float q = rintf(x / s);
  q = fminf(fmaxf(q, -127.f), 127.f);
  return q * s;
}

// reciprocal-mult variant (cheap; boundary flips are ~1e-5 of elems, each worth
// <= one intermediate quant step which attenuates through the following conv)
__device__ __forceinline__ float fqr(float x, float r, float s){
  float q = rintf(x * r);
  q = fminf(fmaxf(q, -127.f), 127.f);
  return q * s;
}

// ---------------- kernels ----------------

__global__ void k_init(unsigned* umax){
  if(threadIdx.x < 4) umax[threadIdx.x] = 0u;
}

// BN-fold + per-channel weight fake-quant. 1248 blocks x 64 threads.
__global__ void k_prep(const float* __restrict__ w1,const float* __restrict__ g1,const float* __restrict__ b1,const float* __restrict__ m1,const float* __restrict__ v1,
                       const float* __restrict__ w2,const float* __restrict__ g2,const float* __restrict__ b2,const float* __restrict__ m2,const float* __restrict__ v2,
                       const float* __restrict__ w3,const float* __restrict__ g3,const float* __restrict__ b3,const float* __restrict__ m3,const float* __restrict__ v3,
                       float* __restrict__ wq1, float* __restrict__ bq1,
                       float* __restrict__ wq2, float* __restrict__ bq2,
                       float* __restrict__ wq3T, float* __restrict__ bq3)
{
  int b = blockIdx.x, lane = threadIdx.x;
  if(b < MIDC){                                   // conv1 weights: row o, 96 elems
    int o = b;
    float f = g1[o] / sqrtf(v1[o] + 1e-5f);
    float x0 = w1[o*CIN + lane] * f;
    float x1 = (lane < CIN-64) ? w1[o*CIN + 64 + lane] * f : 0.f;
    float m = wave_max64(fmaxf(fabsf(x0), fabsf(x1)));
    float s = m / 127.f + 1e-8f;
    wq1[o*CIN + lane] = fq(x0, s);
    if(lane < CIN-64) wq1[o*CIN + 64 + lane] = fq(x1, s);
    if(lane==0) bq1[o] = b1[o] - m1[o]*f;
  } else if(b < 2*MIDC){                          // depthwise weights: channel c, 9 elems
    int c = b - MIDC;
    float f = g2[c] / sqrtf(v2[c] + 1e-5f);
    float x0 = (lane < 9) ? w2[c*9 + lane] * f : 0.f;
    float m = wave_max64(fabsf(x0));
    float s = m / 127.f + 1e-8f;
    if(lane < 9) wq2[c*9 + lane] = fq(x0, s);
    if(lane==0) bq2[c] = b2[c] - m2[c]*f;
  } else {                                        // conv3 weights: out o, 576 elems; store transposed [c][o]
    int o = b - 2*MIDC;
    float f = g3[o] / sqrtf(v3[o] + 1e-5f);
    float xs[9]; float m = 0.f;
    #pragma unroll
    for(int k=0;k<9;k++){ int c = lane + 64*k; xs[k] = w3[o*MIDC + c] * f; m = fmaxf(m, fabsf(xs[k])); }
    m = wave_max64(m);
    float s = m / 127.f + 1e-8f;
    #pragma unroll
    for(int k=0;k<9;k++){ int c = lane + 64*k; wq3T[(size_t)c*COUT + o] = fq(xs[k], s); }
    if(lane==0) bq3[o] = b3[o] - m3[o]*f;
  }
}

__global__ void k_absmax(const float4* __restrict__ x, int n4, unsigned* dst){
  float m = 0.f;
  for(int i = blockIdx.x*blockDim.x + threadIdx.x; i < n4; i += gridDim.x*blockDim.x){
    float4 v = x[i];
    m = fmaxf(m, fmaxf(fmaxf(fabsf(v.x), fabsf(v.y)), fmaxf(fabsf(v.z), fabsf(v.w))));
  }
  block_max_atomic(m, dst);
}

// one-shot quantize of x (true division), fp32 dequant values, same NCHW layout
__global__ __launch_bounds__(256) void k_quantx(const float4* __restrict__ x, const unsigned* __restrict__ umax,
                                                float4* __restrict__ xq)
{
  int i = blockIdx.x*256 + threadIdx.x;          // exactly NX/4 threads
  float s0 = __uint_as_float(umax[0]) / 127.f + 1e-8f;
  float4 v = x[i];
  v.x = fq(v.x, s0); v.y = fq(v.y, s0); v.z = fq(v.z, s0); v.w = fq(v.w, s0);
  xq[i] = v;
}

// 1x1 conv 96->576 + bias + ReLU6. grid (196, 6), o-chunk 96. xq pre-quantized.
template<typename T>
__global__ __launch_bounds__(256) void k_conv1(const float* __restrict__ xq, const float* __restrict__ wq1,
     const float* __restrict__ bq1, unsigned* umax, T* __restrict__ y1)
{
  int tid = blockIdx.x*256 + threadIdx.x;       // 0..50175 = n*784+p
  int n = tid / HW, p = tid - n*HW;
  float xv[CIN];
  const float* xp = xq + (size_t)n*CIN*HW + p;
  #pragma unroll
  for(int c=0;c<CIN;c++) xv[c] = xp[(size_t)c*HW];
  int ob = blockIdx.y * 96;
  T* yp = y1 + (size_t)n*MIDC*HW + p;
  float tmax = 0.f;
  for(int oo=0;oo<96;oo++){
    int o = ob + oo;
    const float* __restrict__ wr = wq1 + o*CIN;  // wave-uniform -> scalar loads
    float acc = bq1[o];
    #pragma unroll
    for(int c=0;c<CIN;c++) acc = fmaf(xv[c], wr[c], acc);
    acc = fminf(fmaxf(acc, 0.f), 6.f);
    tmax = fmaxf(tmax, acc);
    yp[(size_t)o*HW] = (T)acc;
  }
  block_max_atomic(tmax, umax + 1);
}

// depthwise 3x3, pad 1 + bias + ReLU6, quantizing y1 on read. 4096 blocks grid-stride.
template<typename T>
__global__ __launch_bounds__(256) void k_conv2(const T* __restrict__ y1, const float* __restrict__ wq2,
   const float* __restrict__ bq2, unsigned* umax, T* __restrict__ y2)
{
  float s1 = __uint_as_float(umax[1]) / 127.f + 1e-8f;
  float r1 = 1.f / s1;
  float tmax = 0.f;
  for(int tid = blockIdx.x*256 + threadIdx.x; tid < NY; tid += 4096*256){
    int p = tid % HW; int nc = tid / HW; int c = nc % MIDC;
    int h = p / W28, w = p - h*W28;
    const T* bp = y1 + (size_t)nc*HW;
    const float* wr = wq2 + c*9;
    float acc = bq2[c];
    #pragma unroll
    for(int dy=-1;dy<=1;dy++){
      #pragma unroll
      for(int dx=-1;dx<=1;dx++){
        int hh = h+dy, ww = w+dx;
        float v = (hh>=0 && hh<W28 && ww>=0 && ww<W28) ? (float)bp[hh*W28 + ww] : 0.f;
        acc = fmaf(fqr(v, r1, s1), wr[(dy+1)*3 + (dx+1)], acc);
      }
    }
    acc = fminf(fmaxf(acc, 0.f), 6.f);
    tmax = fmaxf(tmax, acc);
    y2[tid] = (T)acc;
  }
  block_max_atomic(tmax, umax + 2);
}

// 1x1 conv 576->96 + bias + identity. grid (196, 4), o-chunk 24, K unrolled x8.
template<typename T>
__global__ __launch_bounds__(256) void k_conv3(const T* __restrict__ y2, const float* __restrict__ wq3T,
   const float* __restrict__ bq3, const float* __restrict__ x, unsigned* umax,
   float* __restrict__ out)
{
  int tid = blockIdx.x*256 + threadIdx.x;
  int n = tid / HW, p = tid - n*HW;
  float s2 = __uint_as_float(umax[2]) / 127.f + 1e-8f;
  float r2 = 1.f / s2;
  int ob = blockIdx.y * 24;
  float acc[24];
  #pragma unroll
  for(int o=0;o<24;o++) acc[o] = bq3[ob + o];
  const T* yp = y2 + (size_t)n*MIDC*HW + p;
  for(int c=0;c<MIDC;c+=8){
    float q[8];
    #pragma unroll
    for(int j=0;j<8;j++) q[j] = fqr((float)yp[(size_t)(c+j)*HW], r2, s2);
    const float* __restrict__ w0 = wq3T + (size_t)c*COUT + ob;   // wave-uniform
    #pragma unroll
    for(int j=0;j<8;j++){
      #pragma unroll
      for(int o=0;o<24;o++) acc[o] = fmaf(q[j], w0[j*COUT + o], acc[o]);
    }
  }
  const float* xp = x + (size_t)n*CIN*HW + p;
  float* op = out + (size_t)n*CIN*HW + p;
  float tmax = 0.f;
  #pragma unroll
  for(int o=0;o<24;o++){
    float y = acc[o] + xp[(size_t)(ob+o)*HW];
    tmax = fmaxf(tmax, fabsf(y));
    op[(size_t)(ob+o)*HW] = y;
  }
  block_max_atomic(tmax, umax + 3);
}

// final per-tensor fake-quant of out (in place) + write scale
__global__ void k_finalq(float* __restrict__ out, const unsigned* __restrict__ umax, float* __restrict__ sf){
  int i = blockIdx.x*256 + threadIdx.x;          // exactly NX/4 threads
  float s3 = __uint_as_float(umax[3]) / 127.f + 1e-8f;
  float4* o4 = (float4*)out;
  float4 v = o4[i];
  v.x = fq(v.x, s3); v.y = fq(v.y, s3); v.z = fq(v.z, s3); v.w = fq(v.w, s3);
  o4[i] = v;
  if(i == 0) *sf = s3;
}

// ---------------- launch ----------------

extern "C" void kernel_launch(void* const* d_in, const int* in_sizes, int n_in,
                              void* d_out, int out_size, void* d_ws, size_t ws_size,
                              hipStream_t stream)
{
  const float* x  = (const float*)d_in[0];
  const float* w1 = (const float*)d_in[1];
  const float* g1 = (const float*)d_in[2];
  const float* b1 = (const float*)d_in[3];
  const float* m1 = (const float*)d_in[4];
  const float* v1 = (const float*)d_in[5];
  const float* w2 = (const float*)d_in[6];
  const float* g2 = (const float*)d_in[7];
  const float* b2 = (const float*)d_in[8];
  const float* m2 = (const float*)d_in[9];
  const float* v2 = (const float*)d_in[10];
  const float* w3 = (const float*)d_in[11];
  const float* g3 = (const float*)d_in[12];
  const float* b3 = (const float*)d_in[13];
  const float* m3 = (const float*)d_in[14];
  const float* v3 = (const float*)d_in[15];

  char* ws = (char*)d_ws;
  unsigned* umax = (unsigned*)(ws + 0);
  float* bq1  = (float*)(ws + 64);
  float* bq2  = (float*)(ws + 2368);
  float* bq3  = (float*)(ws + 4672);
  float* wq1  = (float*)(ws + 5056);
  float* wq2  = (float*)(ws + 226240);
  float* wq3T = (float*)(ws + 246976);
  float* xq   = (float*)(ws + 468224);
  char*  ybase = ws + 468224 + 19267584;         // y1 starts here

  float* outp = (float*)d_out;
  bool fp32path = (ws_size >= 250946816ull);     // xq + 2 fp32 intermediates

  k_init<<<1, 64, 0, stream>>>(umax);
  k_prep<<<1248, 64, 0, stream>>>(w1,g1,b1,m1,v1, w2,g2,b2,m2,v2, w3,g3,b3,m3,v3,
                                  wq1,bq1, wq2,bq2, wq3T,bq3);
  k_absmax<<<1024, 256, 0, stream>>>((const float4*)x, NX/4, umax + 0);
  k_quantx<<<NX/4/256, 256, 0, stream>>>((const float4*)x, umax, (float4*)xq);

  if(fp32path){
    float* y1 = (float*)ybase;
    float* y2 = y1 + (size_t)NY;
    k_conv1<float><<<dim3(196,6), 256, 0, stream>>>(xq, wq1, bq1, umax, y1);
    k_conv2<float><<<4096, 256, 0, stream>>>(y1, wq2, bq2, umax, y2);
    k_conv3<float><<<dim3(196,4), 256, 0, stream>>>(y2, wq3T, bq3, x, umax, outp);
  } else {
    __half* y1 = (__half*)ybase;
    __half* y2 = y1 + (size_t)NY;
    k_conv1<__half><<<dim3(196,6), 256, 0, stream>>>(xq, wq1, bq1, umax, y1);
    k_conv2<__half><<<4096, 256, 0, stream>>>(y1, wq2, bq2, umax, y2);
    k_conv3<__half><<<dim3(196,4), 256, 0, stream>>>(y2, wq3T, bq3, x, umax, outp);
  }

  k_finalq<<<NX/4/256, 256, 0, stream>>>(outp, umax, outp + NX);
}

// Round 4
// 257.176 us; speedup vs baseline: 2.4854x; 1.4044x over previous
//
#include <hip/hip_runtime.h>
#include <hip/hip_fp16.h>

#define CIN   96
#define MIDC  576
#define COUT  96
#define HW    784
#define W28   28
#define NX    4816896        /* 64*96*28*28  */

typedef __attribute__((ext_vector_type(8))) short short8;
typedef __attribute__((ext_vector_type(4))) float floatx4;

// ---------------- helpers ----------------

__device__ __forceinline__ float wave_max64(float v){
  #pragma unroll
  for(int i=32;i>=1;i>>=1) v = fmaxf(v, __shfl_xor(v, i, 64));
  return v;
}

__device__ __forceinline__ void block_max_atomic(float v, unsigned* dst){
  v = wave_max64(v);
  __shared__ float sm[8];
  int lane = threadIdx.x & 63, w = threadIdx.x >> 6;
  if(lane==0) sm[w] = v;
  __syncthreads();
  if(threadIdx.x==0){
    int nw = (blockDim.x + 63) >> 6;
    float m = sm[0];
    for(int i=1;i<nw;i++) m = fmaxf(m, sm[i]);
    atomicMax(dst, __float_as_uint(m));   // v>=0 always: uint order == float order
  }
}

// fake-quant (dequantized result), true division, round-half-even like jnp.round
__device__ __forceinline__ float fq(float x, float s){
  float q = rintf(x / s);
  q = fminf(fmaxf(q, -127.f), 127.f);
  return q * s;
}

// integer part of the quantization (true division)
__device__ __forceinline__ float qint(float x, float s){
  return fminf(fmaxf(rintf(x / s), -127.f), 127.f);
}

// fp32 (integer-valued, |v|<=127) -> bf16 bits, exact
__device__ __forceinline__ ushort f2bf(float f){
  return (ushort)(__float_as_uint(f) >> 16);
}

// ---------------- kernels ----------------

__global__ void k_init(unsigned* umax){
  if(threadIdx.x < 4) umax[threadIdx.x] = 0u;
}

// BN-fold + per-channel weight quant. Integer bf16 for conv1/conv3, dequant fp32 for dw.
__global__ void k_prep(const float* __restrict__ w1,const float* __restrict__ g1,const float* __restrict__ b1,const float* __restrict__ m1,const float* __restrict__ v1,
                       const float* __restrict__ w2,const float* __restrict__ g2,const float* __restrict__ b2,const float* __restrict__ m2,const float* __restrict__ v2,
                       const float* __restrict__ w3,const float* __restrict__ g3,const float* __restrict__ b3,const float* __restrict__ m3,const float* __restrict__ v3,
                       ushort* __restrict__ qw1, float* __restrict__ sc1, float* __restrict__ bq1,
                       float*  __restrict__ wq2, float* __restrict__ bq2,
                       ushort* __restrict__ qw3, float* __restrict__ sc3, float* __restrict__ bq3)
{
  int b = blockIdx.x, lane = threadIdx.x;
  if(b < MIDC){                                   // conv1 weights: row o, 96 elems
    int o = b;
    float f = g1[o] / sqrtf(v1[o] + 1e-5f);
    float x0 = w1[o*CIN + lane] * f;
    float x1 = (lane < 32) ? w1[o*CIN + 64 + lane] * f : 0.f;
    float m = wave_max64(fmaxf(fabsf(x0), fabsf(x1)));
    float s = m / 127.f + 1e-8f;
    qw1[o*CIN + lane] = f2bf(qint(x0, s));
    if(lane < 32) qw1[o*CIN + 64 + lane] = f2bf(qint(x1, s));
    if(lane==0){ sc1[o] = s; bq1[o] = b1[o] - m1[o]*f; }
  } else if(b < 2*MIDC){                          // depthwise weights: channel c, 9 elems
    int c = b - MIDC;
    float f = g2[c] / sqrtf(v2[c] + 1e-5f);
    float x0 = (lane < 9) ? w2[c*9 + lane] * f : 0.f;
    float m = wave_max64(fabsf(x0));
    float s = m / 127.f + 1e-8f;
    if(lane < 9) wq2[c*9 + lane] = fq(x0, s);
    if(lane==0) bq2[c] = b2[c] - m2[c]*f;
  } else {                                        // conv3 weights: row o, 576 elems (k-contiguous)
    int o = b - 2*MIDC;
    float f = g3[o] / sqrtf(v3[o] + 1e-5f);
    float xs[9]; float m = 0.f;
    #pragma unroll
    for(int k=0;k<9;k++){ int c = lane + 64*k; xs[k] = w3[o*MIDC + c] * f; m = fmaxf(m, fabsf(xs[k])); }
    m = wave_max64(m);
    float s = m / 127.f + 1e-8f;
    #pragma unroll
    for(int k=0;k<9;k++){ int c = lane + 64*k; qw3[o*MIDC + c] = f2bf(qint(xs[k], s)); }
    if(lane==0){ sc3[o] = s; bq3[o] = b3[o] - m3[o]*f; }
  }
}

__global__ void k_absmax(const float4* __restrict__ x, int n4, unsigned* dst){
  float m = 0.f;
  for(int i = blockIdx.x*blockDim.x + threadIdx.x; i < n4; i += gridDim.x*blockDim.x){
    float4 v = x[i];
    m = fmaxf(m, fmaxf(fmaxf(fabsf(v.x), fabsf(v.y)), fmaxf(fabsf(v.z), fabsf(v.w))));
  }
  block_max_atomic(m, dst);
}

// x [n][96][784] fp32 -> qxT [(n*784+p)][96] bf16 integers, LDS transpose. grid (64,14)
__global__ __launch_bounds__(256) void k_quantxT(const float* __restrict__ x,
    const unsigned* __restrict__ umax, ushort* __restrict__ qxT)
{
  __shared__ ushort lds[56*100];
  int n = blockIdx.x, pc = blockIdx.y, tid = threadIdx.x;
  float s0 = __uint_as_float(umax[0])/127.f + 1e-8f;
  for(int i = tid; i < 96*56; i += 256){
    int c = i/56, p = i - c*56;
    float v = x[(size_t)(n*CIN + c)*HW + pc*56 + p];
    lds[p*100 + c] = f2bf(qint(v, s0));
  }
  __syncthreads();
  const uint* lu = (const uint*)lds;
  uint* q = (uint*)qxT;
  for(int i = tid; i < 56*48; i += 256){
    int r = i/48, d = i - r*48;
    q[(size_t)(n*HW + pc*56 + r)*48 + d] = lu[r*50 + d];
  }
}

// 1x1 conv 96->576 via MFMA. grid (64 n, 9 mtile) x 256 thr (4 waves, 16 rows each).
__global__ __launch_bounds__(256) void k_conv1(const ushort* __restrict__ qxT,
    const ushort* __restrict__ qw1, const float* __restrict__ sc1, const float* __restrict__ bq1,
    unsigned* umax, __half* __restrict__ y1)
{
  int n = blockIdx.x, mt = blockIdx.y;
  int w = threadIdx.x >> 6, l = threadIdx.x & 63;
  int lhi = l >> 4, llo = l & 15;
  int m0 = mt*64 + w*16;
  float s0 = __uint_as_float(umax[0])/127.f + 1e-8f;
  short8 a[3];
  #pragma unroll
  for(int ks=0; ks<3; ks++)
    a[ks] = *(const short8*)(qw1 + (m0 + llo)*CIN + ks*32 + lhi*8);
  float scf[4], bf[4];
  #pragma unroll
  for(int r=0;r<4;r++){ int o = m0 + lhi*4 + r; scf[r] = s0*sc1[o]; bf[r] = bq1[o]; }
  float tmax = 0.f;
  for(int ch=0; ch<7; ch++){
    int p0 = ch*112;
    floatx4 acc[7];
    #pragma unroll
    for(int f=0;f<7;f++) acc[f] = (floatx4){0.f,0.f,0.f,0.f};
    #pragma unroll
    for(int ks=0; ks<3; ks++){
      #pragma unroll
      for(int f=0; f<7; f++){
        const short8 b = *(const short8*)(qxT + (size_t)(n*HW + p0 + f*16 + llo)*CIN + ks*32 + lhi*8);
        acc[f] = __builtin_amdgcn_mfma_f32_16x16x32_bf16(a[ks], b, acc[f], 0, 0, 0);
      }
    }
    #pragma unroll
    for(int f=0; f<7; f++){
      #pragma unroll
      for(int r=0;r<4;r++){
        float v = fmaf(acc[f][r], scf[r], bf[r]);
        v = fminf(fmaxf(v, 0.f), 6.f);
        tmax = fmaxf(tmax, v);
        y1[(size_t)(n*MIDC + m0 + lhi*4 + r)*HW + p0 + f*16 + llo] = __float2half(v);
      }
    }
  }
  block_max_atomic(tmax, umax + 1);
}

// depthwise 3x3 pad1 + ReLU6; quantize y1 ONCE into LDS. grid (72 cgroups, 64 n)
__global__ __launch_bounds__(256) void k_conv2(const __half* __restrict__ y1,
    const float* __restrict__ wq2, const float* __restrict__ bq2,
    unsigned* umax, __half* __restrict__ y2)
{
  __shared__ float lds[8*HW];
  int cg = blockIdx.x, n = blockIdx.y, tid = threadIdx.x;
  float s1 = __uint_as_float(umax[1])/127.f + 1e-8f;
  for(int i = tid; i < 8*HW; i += 256){
    int c8 = i/HW, p = i - c8*HW;
    float v = __half2float(y1[(size_t)(n*MIDC + cg*8 + c8)*HW + p]);
    lds[i] = fq(v, s1);
  }
  __syncthreads();
  float tmax = 0.f;
  for(int i = tid; i < 8*HW; i += 256){
    int c8 = i/HW, p = i - c8*HW;
    int c = cg*8 + c8;
    int h = p/W28, ww = p - h*W28;
    const float* wr = wq2 + c*9;
    const float* bp = lds + c8*HW;
    float acc = bq2[c];
    #pragma unroll
    for(int dy=-1;dy<=1;dy++){
      int hh = h+dy;
      #pragma unroll
      for(int dx=-1;dx<=1;dx++){
        int wx = ww+dx;
        float v = (hh>=0 && hh<W28 && wx>=0 && wx<W28) ? bp[hh*W28+wx] : 0.f;
        acc = fmaf(v, wr[(dy+1)*3+(dx+1)], acc);
      }
    }
    acc = fminf(fmaxf(acc, 0.f), 6.f);
    tmax = fmaxf(tmax, acc);
    y2[(size_t)(n*MIDC + c)*HW + p] = __float2half(acc);
  }
  block_max_atomic(tmax, umax + 2);
}

// y2 [n][576][784] fp16 -> qy2T [(n*784+p)][576] bf16 integers. grid (64,14)
__global__ __launch_bounds__(256) void k_quanty2T(const __half* __restrict__ y2,
    const unsigned* __restrict__ umax, ushort* __restrict__ qy2T)
{
  __shared__ ushort lds[56*292];
  int n = blockIdx.x, pc = blockIdx.y, tid = threadIdx.x;
  float s2 = __uint_as_float(umax[2])/127.f + 1e-8f;
  for(int ch2 = 0; ch2 < 2; ch2++){
    for(int i = tid; i < 288*56; i += 256){
      int c = i/56, p = i - c*56;
      float v = __half2float(y2[(size_t)(n*MIDC + ch2*288 + c)*HW + pc*56 + p]);
      lds[p*292 + c] = f2bf(qint(v, s2));
    }
    __syncthreads();
    const uint* lu = (const uint*)lds;
    uint* q = (uint*)qy2T;
    for(int i = tid; i < 56*144; i += 256){
      int r = i/144, d = i - r*144;
      q[(size_t)(n*HW + pc*56 + r)*288 + ch2*144 + d] = lu[r*146 + d];
    }
    __syncthreads();
  }
}

// 1x1 conv 576->96 via MFMA + bias + identity. grid (64 n, 7 colgroup) x 384 thr (6 waves).
__global__ __launch_bounds__(384) void k_conv3(const ushort* __restrict__ qy2T,
    const ushort* __restrict__ qw3, const float* __restrict__ sc3, const float* __restrict__ bq3,
    const float* __restrict__ x, unsigned* umax, float* __restrict__ out)
{
  int n = blockIdx.x, cgp = blockIdx.y;
  int w = threadIdx.x >> 6, l = threadIdx.x & 63;
  int lhi = l >> 4, llo = l & 15;
  int m0 = w*16;
  int p0 = cgp*112;
  float s2 = __uint_as_float(umax[2])/127.f + 1e-8f;
  float scf[4], bf[4];
  #pragma unroll
  for(int r=0;r<4;r++){ int o = m0 + lhi*4 + r; scf[r] = s2*sc3[o]; bf[r] = bq3[o]; }
  floatx4 acc[7];
  #pragma unroll
  for(int f=0;f<7;f++) acc[f] = (floatx4){0.f,0.f,0.f,0.f};
  for(int ks=0; ks<18; ks++){
    const short8 a = *(const short8*)(qw3 + (m0 + llo)*MIDC + ks*32 + lhi*8);
    #pragma unroll
    for(int f=0; f<7; f++){
      const short8 b = *(const short8*)(qy2T + (size_t)(n*HW + p0 + f*16 + llo)*MIDC + ks*32 + lhi*8);
      acc[f] = __builtin_amdgcn_mfma_f32_16x16x32_bf16(a, b, acc[f], 0, 0, 0);
    }
  }
  float tmax = 0.f;
  #pragma unroll
  for(int f=0; f<7; f++){
    #pragma unroll
    for(int r=0;r<4;r++){
      size_t idx = (size_t)(n*COUT + m0 + lhi*4 + r)*HW + p0 + f*16 + llo;
      float v = fmaf(acc[f][r], scf[r], bf[r]) + x[idx];
      tmax = fmaxf(tmax, fabsf(v));
      out[idx] = v;
    }
  }
  block_max_atomic(tmax, umax + 3);
}

// final per-tensor fake-quant of out (in place) + write scale
__global__ void k_finalq(float* __restrict__ out, const unsigned* __restrict__ umax, float* __restrict__ sf){
  int i = blockIdx.x*256 + threadIdx.x;          // exactly NX/4 threads
  float s3 = __uint_as_float(umax[3]) / 127.f + 1e-8f;
  float4* o4 = (float4*)out;
  float4 v = o4[i];
  v.x = fq(v.x, s3); v.y = fq(v.y, s3); v.z = fq(v.z, s3); v.w = fq(v.w, s3);
  o4[i] = v;
  if(i == 0) *sf = s3;
}

// ---------------- launch ----------------

extern "C" void kernel_launch(void* const* d_in, const int* in_sizes, int n_in,
                              void* d_out, int out_size, void* d_ws, size_t ws_size,
                              hipStream_t stream)
{
  const float* x  = (const float*)d_in[0];
  const float* w1 = (const float*)d_in[1];
  const float* g1 = (const float*)d_in[2];
  const float* b1 = (const float*)d_in[3];
  const float* m1 = (const float*)d_in[4];
  const float* v1 = (const float*)d_in[5];
  const float* w2 = (const float*)d_in[6];
  const float* g2 = (const float*)d_in[7];
  const float* b2 = (const float*)d_in[8];
  const float* m2 = (const float*)d_in[9];
  const float* v2 = (const float*)d_in[10];
  const float* w3 = (const float*)d_in[11];
  const float* g3 = (const float*)d_in[12];
  const float* b3 = (const float*)d_in[13];
  const float* m3 = (const float*)d_in[14];
  const float* v3 = (const float*)d_in[15];

  char* ws = (char*)d_ws;
  unsigned* umax = (unsigned*)(ws + 0);
  float* sc1  = (float*)(ws + 256);
  float* bq1  = (float*)(ws + 2560);
  float* bq2  = (float*)(ws + 4864);
  float* wq2  = (float*)(ws + 7168);
  float* sc3  = (float*)(ws + 27904);
  float* bq3  = (float*)(ws + 28288);
  ushort* qw1 = (ushort*)(ws + 28672);
  ushort* qw3 = (ushort*)(ws + 139264);
  ushort* qxT = (ushort*)(ws + 249856);
  char*  bufA = ws + 9883648;                    // y1 (fp16), later qy2T (bf16) - same size
  char*  bufB = ws + 67686400;                   // y2 (fp16)

  __half* y1   = (__half*)bufA;
  __half* y2   = (__half*)bufB;
  ushort* qy2T = (ushort*)bufA;

  float* outp = (float*)d_out;

  k_init<<<1, 64, 0, stream>>>(umax);
  k_prep<<<1248, 64, 0, stream>>>(w1,g1,b1,m1,v1, w2,g2,b2,m2,v2, w3,g3,b3,m3,v3,
                                  qw1,sc1,bq1, wq2,bq2, qw3,sc3,bq3);
  k_absmax<<<1024, 256, 0, stream>>>((const float4*)x, NX/4, umax + 0);
  k_quantxT<<<dim3(64,14), 256, 0, stream>>>(x, umax, qxT);
  k_conv1<<<dim3(64,9), 256, 0, stream>>>(qxT, qw1, sc1, bq1, umax, y1);
  k_conv2<<<dim3(72,64), 256, 0, stream>>>(y1, wq2, bq2, umax, y2);
  k_quanty2T<<<dim3(64,14), 256, 0, stream>>>(y2, umax, qy2T);
  k_conv3<<<dim3(64,7), 384, 0, stream>>>(qy2T, qw3, sc3, bq3, x, umax, outp);
  k_finalq<<<NX/4/256, 256, 0, stream>>>(outp, umax, outp + NX);
}

// Round 5
// 241.101 us; speedup vs baseline: 2.6512x; 1.0667x over previous
//
#include <hip/hip_runtime.h>
#include <hip/hip_fp16.h>

#define CIN   96
#define MIDC  576
#define COUT  96
#define HW    784
#define W28   28
#define NX    4816896        /* 64*96*28*28  */
#define TW    32             /* padded tile row width (floats) */
#define TH    30             /* padded tile rows per channel   */

typedef __attribute__((ext_vector_type(8))) short short8;
typedef __attribute__((ext_vector_type(4))) float floatx4;

// ---------------- helpers ----------------

__device__ __forceinline__ float wave_max64(float v){
  #pragma unroll
  for(int i=32;i>=1;i>>=1) v = fmaxf(v, __shfl_xor(v, i, 64));
  return v;
}

__device__ __forceinline__ void block_max_atomic(float v, unsigned* dst){
  v = wave_max64(v);
  __shared__ float sm[8];
  int lane = threadIdx.x & 63, w = threadIdx.x >> 6;
  if(lane==0) sm[w] = v;
  __syncthreads();
  if(threadIdx.x==0){
    int nw = (blockDim.x + 63) >> 6;
    float m = sm[0];
    for(int i=1;i<nw;i++) m = fmaxf(m, sm[i]);
    atomicMax(dst, __float_as_uint(m));   // v>=0 always: uint order == float order
  }
}

// fake-quant (dequantized result), true division, round-half-even like jnp.round
__device__ __forceinline__ float fq(float x, float s){
  float q = rintf(x / s);
  q = fminf(fmaxf(q, -127.f), 127.f);
  return q * s;
}

// reciprocal-mult variant (boundary flips ~1e-5 of elems, each <= one quant step)
__device__ __forceinline__ float fqr(float x, float r, float s){
  float q = rintf(x * r);
  q = fminf(fmaxf(q, -127.f), 127.f);
  return q * s;
}

// integer part of the quantization (true division)
__device__ __forceinline__ float qint(float x, float s){
  return fminf(fmaxf(rintf(x / s), -127.f), 127.f);
}

// fp32 (integer-valued, |v|<=127) -> bf16 bits, exact
__device__ __forceinline__ ushort f2bf(float f){
  return (ushort)(__float_as_uint(f) >> 16);
}

// ---------------- kernels ----------------

__global__ void k_init(unsigned* umax){
  if(threadIdx.x < 4) umax[threadIdx.x] = 0u;
}

// BN-fold + per-channel weight quant. Integer bf16 for conv1/conv3, dequant fp32 for dw.
__global__ void k_prep(const float* __restrict__ w1,const float* __restrict__ g1,const float* __restrict__ b1,const float* __restrict__ m1,const float* __restrict__ v1,
                       const float* __restrict__ w2,const float* __restrict__ g2,const float* __restrict__ b2,const float* __restrict__ m2,const float* __restrict__ v2,
                       const float* __restrict__ w3,const float* __restrict__ g3,const float* __restrict__ b3,const float* __restrict__ m3,const float* __restrict__ v3,
                       ushort* __restrict__ qw1, float* __restrict__ sc1, float* __restrict__ bq1,
                       float*  __restrict__ wq2, float* __restrict__ bq2,
                       ushort* __restrict__ qw3, float* __restrict__ sc3, float* __restrict__ bq3)
{
  int b = blockIdx.x, lane = threadIdx.x;
  if(b < MIDC){                                   // conv1 weights: row o, 96 elems
    int o = b;
    float f = g1[o] / sqrtf(v1[o] + 1e-5f);
    float x0 = w1[o*CIN + lane] * f;
    float x1 = (lane < 32) ? w1[o*CIN + 64 + lane] * f : 0.f;
    float m = wave_max64(fmaxf(fabsf(x0), fabsf(x1)));
    float s = m / 127.f + 1e-8f;
    qw1[o*CIN + lane] = f2bf(qint(x0, s));
    if(lane < 32) qw1[o*CIN + 64 + lane] = f2bf(qint(x1, s));
    if(lane==0){ sc1[o] = s; bq1[o] = b1[o] - m1[o]*f; }
  } else if(b < 2*MIDC){                          // depthwise weights: channel c, 9 elems
    int c = b - MIDC;
    float f = g2[c] / sqrtf(v2[c] + 1e-5f);
    float x0 = (lane < 9) ? w2[c*9 + lane] * f : 0.f;
    float m = wave_max64(fabsf(x0));
    float s = m / 127.f + 1e-8f;
    if(lane < 9) wq2[c*9 + lane] = fq(x0, s);
    if(lane==0) bq2[c] = b2[c] - m2[c]*f;
  } else {                                        // conv3 weights: row o, 576 elems (k-contiguous)
    int o = b - 2*MIDC;
    float f = g3[o] / sqrtf(v3[o] + 1e-5f);
    float xs[9]; float m = 0.f;
    #pragma unroll
    for(int k=0;k<9;k++){ int c = lane + 64*k; xs[k] = w3[o*MIDC + c] * f; m = fmaxf(m, fabsf(xs[k])); }
    m = wave_max64(m);
    float s = m / 127.f + 1e-8f;
    #pragma unroll
    for(int k=0;k<9;k++){ int c = lane + 64*k; qw3[o*MIDC + c] = f2bf(qint(xs[k], s)); }
    if(lane==0){ sc3[o] = s; bq3[o] = b3[o] - m3[o]*f; }
  }
}

__global__ void k_absmax(const float4* __restrict__ x, int n4, unsigned* dst){
  float m = 0.f;
  for(int i = blockIdx.x*blockDim.x + threadIdx.x; i < n4; i += gridDim.x*blockDim.x){
    float4 v = x[i];
    m = fmaxf(m, fmaxf(fmaxf(fabsf(v.x), fabsf(v.y)), fmaxf(fabsf(v.z), fabsf(v.w))));
  }
  block_max_atomic(m, dst);
}

// x [n][96][784] fp32 -> qxT [(n*784+p)][96] bf16 integers, LDS transpose. grid (64,14)
__global__ __launch_bounds__(256) void k_quantxT(const float* __restrict__ x,
    const unsigned* __restrict__ umax, ushort* __restrict__ qxT)
{
  __shared__ ushort lds[56*100];
  int n = blockIdx.x, pc = blockIdx.y, tid = threadIdx.x;
  float s0 = __uint_as_float(umax[0])/127.f + 1e-8f;
  for(int i = tid; i < 96*56; i += 256){
    int c = i/56, p = i - c*56;
    float v = x[(size_t)(n*CIN + c)*HW + pc*56 + p];
    lds[p*100 + c] = f2bf(qint(v, s0));
  }
  __syncthreads();
  const uint* lu = (const uint*)lds;
  uint* q = (uint*)qxT;
  for(int i = tid; i < 56*48; i += 256){
    int r = i/48, d = i - r*48;
    q[(size_t)(n*HW + pc*56 + r)*48 + d] = lu[r*50 + d];
  }
}

// 1x1 conv 96->576 via MFMA. grid (64 n, 9 mtile) x 256 thr (4 waves, 16 rows each).
__global__ __launch_bounds__(256) void k_conv1(const ushort* __restrict__ qxT,
    const ushort* __restrict__ qw1, const float* __restrict__ sc1, const float* __restrict__ bq1,
    unsigned* umax, __half* __restrict__ y1)
{
  int n = blockIdx.x, mt = blockIdx.y;
  int w = threadIdx.x >> 6, l = threadIdx.x & 63;
  int lhi = l >> 4, llo = l & 15;
  int m0 = mt*64 + w*16;
  float s0 = __uint_as_float(umax[0])/127.f + 1e-8f;
  short8 a[3];
  #pragma unroll
  for(int ks=0; ks<3; ks++)
    a[ks] = *(const short8*)(qw1 + (m0 + llo)*CIN + ks*32 + lhi*8);
  float scf[4], bf[4];
  #pragma unroll
  for(int r=0;r<4;r++){ int o = m0 + lhi*4 + r; scf[r] = s0*sc1[o]; bf[r] = bq1[o]; }
  float tmax = 0.f;
  for(int ch=0; ch<7; ch++){
    int p0 = ch*112;
    floatx4 acc[7];
    #pragma unroll
    for(int f=0;f<7;f++) acc[f] = (floatx4){0.f,0.f,0.f,0.f};
    #pragma unroll
    for(int ks=0; ks<3; ks++){
      #pragma unroll
      for(int f=0; f<7; f++){
        const short8 b = *(const short8*)(qxT + (size_t)(n*HW + p0 + f*16 + llo)*CIN + ks*32 + lhi*8);
        acc[f] = __builtin_amdgcn_mfma_f32_16x16x32_bf16(a[ks], b, acc[f], 0, 0, 0);
      }
    }
    #pragma unroll
    for(int f=0; f<7; f++){
      #pragma unroll
      for(int r=0;r<4;r++){
        float v = fmaf(acc[f][r], scf[r], bf[r]);
        v = fminf(fmaxf(v, 0.f), 6.f);
        tmax = fmaxf(tmax, v);
        y1[(size_t)(n*MIDC + m0 + lhi*4 + r)*HW + p0 + f*16 + llo] = __float2half(v);
      }
    }
  }
  block_max_atomic(tmax, umax + 1);
}

// depthwise 3x3 pad1 + ReLU6. Row-based: zero-padded swizzled LDS tile, no boundary
// compares, register-shift taps. grid (72 cgroups, 64 n) x 256.
__global__ __launch_bounds__(256) void k_conv2(const __half* __restrict__ y1,
    const float* __restrict__ wq2, const float* __restrict__ bq2,
    unsigned* umax, __half* __restrict__ y2)
{
  __shared__ float lds[8*TH*TW];                 // 30720 B, swizzled rows
  int cg = blockIdx.x, n = blockIdx.y, tid = threadIdx.x;
  float s1 = __uint_as_float(umax[1])/127.f + 1e-8f;
  float r1 = 1.f/s1;

  // zero-fill (pads rows 0,29 and cols 0,29..31)
  float4* l4 = (float4*)lds;
  for(int i = tid; i < 8*TH*TW/4; i += 256) l4[i] = (float4){0.f,0.f,0.f,0.f};
  __syncthreads();

  // stage: quantize y1 once, half2 loads. data col w -> logical idx w+1, row h -> padded h+1
  const __half2* yb = (const __half2*)(y1 + (size_t)(n*MIDC + cg*8)*HW);
  for(int j = tid; j < 8*HW/2; j += 256){
    int c8 = j/(HW/2), pp = j - c8*(HW/2);
    int p = pp*2;
    __half2 hv = yb[c8*(HW/2) + pp];
    int h = p/W28, w = p - h*W28;               // w even, w+1 <= 27: same row
    int row = c8*TH + h + 1;
    int sw = row & 7;
    int i0 = w+1, i1 = w+2;
    lds[row*TW + ((((i0>>2)^sw)<<2) | (i0&3))] = fqr(__half2float(hv.x), r1, s1);
    lds[row*TW + ((((i1>>2)^sw)<<2) | (i1&3))] = fqr(__half2float(hv.y), r1, s1);
  }
  __syncthreads();

  // compute: thread = (c8, output row h), 224 active
  float tmax = 0.f;
  float acc[28];
  int c8 = tid/28, h = tid - c8*28;
  if(tid < 224){
    int c = cg*8 + c8;
    float wv[9];
    #pragma unroll
    for(int k=0;k<9;k++) wv[k] = wq2[c*9 + k];
    float bb = bq2[c];
    #pragma unroll
    for(int w=0;w<28;w++) acc[w] = bb;
    #pragma unroll
    for(int dy=0; dy<3; dy++){
      int row = c8*TH + h + dy;                 // padded rows h..h+2
      int sw = row & 7;
      float r[32];
      floatx4* rp = (floatx4*)r;
      #pragma unroll
      for(int ch=0; ch<8; ch++)
        rp[ch] = *(const floatx4*)&lds[row*TW + ((ch^sw)<<2)];
      #pragma unroll
      for(int w=0;w<28;w++){
        acc[w] = fmaf(r[w],   wv[dy*3+0], acc[w]);
        acc[w] = fmaf(r[w+1], wv[dy*3+1], acc[w]);
        acc[w] = fmaf(r[w+2], wv[dy*3+2], acc[w]);
      }
    }
    #pragma unroll
    for(int w=0;w<28;w++){
      acc[w] = fminf(fmaxf(acc[w], 0.f), 6.f);
      tmax = fmaxf(tmax, acc[w]);
    }
  }
  __syncthreads();                               // all tile reads done

  // restage outputs (fp16 pairs) into LDS for coalesced writes
  uint* os32 = (uint*)lds;
  if(tid < 224){
    int ob = c8*(HW/2) + h*14;
    #pragma unroll
    for(int k=0;k<14;k++){
      uint lo = (uint)__half_as_ushort(__float2half(acc[2*k]));
      uint hi = (uint)__half_as_ushort(__float2half(acc[2*k+1]));
      os32[ob + k] = (hi<<16) | lo;
    }
  }
  __syncthreads();

  float4* og = (float4*)(y2 + (size_t)(n*MIDC + cg*8)*HW);
  const float4* l4b = (const float4*)lds;
  for(int i = tid; i < 8*HW*2/16; i += 256) og[i] = l4b[i];

  block_max_atomic(tmax, umax + 2);
}

// y2 [n][576][784] fp16 -> qy2T [(n*784+p)][576] bf16 integers. grid (64,14)
__global__ __launch_bounds__(256) void k_quanty2T(const __half* __restrict__ y2,
    const unsigned* __restrict__ umax, ushort* __restrict__ qy2T)
{
  __shared__ ushort lds[56*292];
  int n = blockIdx.x, pc = blockIdx.y, tid = threadIdx.x;
  float s2 = __uint_as_float(umax[2])/127.f + 1e-8f;
  for(int ch2 = 0; ch2 < 2; ch2++){
    for(int i = tid; i < 288*56; i += 256){
      int c = i/56, p = i - c*56;
      float v = __half2float(y2[(size_t)(n*MIDC + ch2*288 + c)*HW + pc*56 + p]);
      lds[p*292 + c] = f2bf(qint(v, s2));
    }
    __syncthreads();
    const uint* lu = (const uint*)lds;
    uint* q = (uint*)qy2T;
    for(int i = tid; i < 56*144; i += 256){
      int r = i/144, d = i - r*144;
      q[(size_t)(n*HW + pc*56 + r)*288 + ch2*144 + d] = lu[r*146 + d];
    }
    __syncthreads();
  }
}

// 1x1 conv 576->96 via MFMA + bias + identity. grid (64 n, 7 colgroup) x 384 thr (6 waves).
__global__ __launch_bounds__(384) void k_conv3(const ushort* __restrict__ qy2T,
    const ushort* __restrict__ qw3, const float* __restrict__ sc3, const float* __restrict__ bq3,
    const float* __restrict__ x, unsigned* umax, float* __restrict__ out)
{
  int n = blockIdx.x, cgp = blockIdx.y;
  int w = threadIdx.x >> 6, l = threadIdx.x & 63;
  int lhi = l >> 4, llo = l & 15;
  int m0 = w*16;
  int p0 = cgp*112;
  float s2 = __uint_as_float(umax[2])/127.f + 1e-8f;
  float scf[4], bf[4];
  #pragma unroll
  for(int r=0;r<4;r++){ int o = m0 + lhi*4 + r; scf[r] = s2*sc3[o]; bf[r] = bq3[o]; }
  floatx4 acc[7];
  #pragma unroll
  for(int f=0;f<7;f++) acc[f] = (floatx4){0.f,0.f,0.f,0.f};
  for(int ks=0; ks<18; ks++){
    const short8 a = *(const short8*)(qw3 + (m0 + llo)*MIDC + ks*32 + lhi*8);
    #pragma unroll
    for(int f=0; f<7; f++){
      const short8 b = *(const short8*)(qy2T + (size_t)(n*HW + p0 + f*16 + llo)*MIDC + ks*32 + lhi*8);
      acc[f] = __builtin_amdgcn_mfma_f32_16x16x32_bf16(a, b, acc[f], 0, 0, 0);
    }
  }
  float tmax = 0.f;
  #pragma unroll
  for(int f=0; f<7; f++){
    #pragma unroll
    for(int r=0;r<4;r++){
      size_t idx = (size_t)(n*COUT + m0 + lhi*4 + r)*HW + p0 + f*16 + llo;
      float v = fmaf(acc[f][r], scf[r], bf[r]) + x[idx];
      tmax = fmaxf(tmax, fabsf(v));
      out[idx] = v;
    }
  }
  block_max_atomic(tmax, umax + 3);
}

// final per-tensor fake-quant of out (in place) + write scale
__global__ void k_finalq(float* __restrict__ out, const unsigned* __restrict__ umax, float* __restrict__ sf){
  int i = blockIdx.x*256 + threadIdx.x;          // exactly NX/4 threads
  float s3 = __uint_as_float(umax[3]) / 127.f + 1e-8f;
  float4* o4 = (float4*)out;
  float4 v = o4[i];
  v.x = fq(v.x, s3); v.y = fq(v.y, s3); v.z = fq(v.z, s3); v.w = fq(v.w, s3);
  o4[i] = v;
  if(i == 0) *sf = s3;
}

// ---------------- launch ----------------

extern "C" void kernel_launch(void* const* d_in, const int* in_sizes, int n_in,
                              void* d_out, int out_size, void* d_ws, size_t ws_size,
                              hipStream_t stream)
{
  const float* x  = (const float*)d_in[0];
  const float* w1 = (const float*)d_in[1];
  const float* g1 = (const float*)d_in[2];
  const float* b1 = (const float*)d_in[3];
  const float* m1 = (const float*)d_in[4];
  const float* v1 = (const float*)d_in[5];
  const float* w2 = (const float*)d_in[6];
  const float* g2 = (const float*)d_in[7];
  const float* b2 = (const float*)d_in[8];
  const float* m2 = (const float*)d_in[9];
  const float* v2 = (const float*)d_in[10];
  const float* w3 = (const float*)d_in[11];
  const float* g3 = (const float*)d_in[12];
  const float* b3 = (const float*)d_in[13];
  const float* m3 = (const float*)d_in[14];
  const float* v3 = (const float*)d_in[15];

  char* ws = (char*)d_ws;
  unsigned* umax = (unsigned*)(ws + 0);
  float* sc1  = (float*)(ws + 256);
  float* bq1  = (float*)(ws + 2560);
  float* bq2  = (float*)(ws + 4864);
  float* wq2  = (float*)(ws + 7168);
  float* sc3  = (float*)(ws + 27904);
  float* bq3  = (float*)(ws + 28288);
  ushort* qw1 = (ushort*)(ws + 28672);
  ushort* qw3 = (ushort*)(ws + 139264);
  ushort* qxT = (ushort*)(ws + 249856);
  char*  bufA = ws + 9883648;                    // y1 (fp16), later qy2T (bf16) - same size
  char*  bufB = ws + 67686400;                   // y2 (fp16)

  __half* y1   = (__half*)bufA;
  __half* y2   = (__half*)bufB;
  ushort* qy2T = (ushort*)bufA;

  float* outp = (float*)d_out;

  k_init<<<1, 64, 0, stream>>>(umax);
  k_prep<<<1248, 64, 0, stream>>>(w1,g1,b1,m1,v1, w2,g2,b2,m2,v2, w3,g3,b3,m3,v3,
                                  qw1,sc1,bq1, wq2,bq2, qw3,sc3,bq3);
  k_absmax<<<1024, 256, 0, stream>>>((const float4*)x, NX/4, umax + 0);
  k_quantxT<<<dim3(64,14), 256, 0, stream>>>(x, umax, qxT);
  k_conv1<<<dim3(64,9), 256, 0, stream>>>(qxT, qw1, sc1, bq1, umax, y1);
  k_conv2<<<dim3(72,64), 256, 0, stream>>>(y1, wq2, bq2, umax, y2);
  k_quanty2T<<<dim3(64,14), 256, 0, stream>>>(y2, umax, qy2T);
  k_conv3<<<dim3(64,7), 384, 0, stream>>>(qy2T, qw3, sc3, bq3, x, umax, outp);
  k_finalq<<<NX/4/256, 256, 0, stream>>>(outp, umax, outp + NX);
}